// Round 2
// baseline (559.226 us; speedup 1.0000x reference)
//
#include <hip/hip_runtime.h>
#include <hip/hip_cooperative_groups.h>
#include <cstdint>

namespace cg = cooperative_groups;

#define F 64
#define COOP_BLOCKS 256
#define COOP_THREADS 1024

typedef short bf16x8 __attribute__((ext_vector_type(8)));
typedef float f32x4  __attribute__((ext_vector_type(4)));

// ---------------------------------------------------------------------------
// bf16 helpers
// ---------------------------------------------------------------------------
__device__ __forceinline__ unsigned short f2b(float f) {     // RNE round
    unsigned u = __float_as_uint(f);
    unsigned r = u + 0x7fffu + ((u >> 16) & 1u);
    return (unsigned short)(r >> 16);
}
__device__ __forceinline__ void add8(float* a, uint4 u) {
    const unsigned* p = (const unsigned*)&u;
#pragma unroll
    for (int i = 0; i < 4; ++i) {
        a[2 * i + 0] += __uint_as_float(p[i] << 16);
        a[2 * i + 1] += __uint_as_float(p[i] & 0xffff0000u);
    }
}

// ---------------------------------------------------------------------------
// Cooperative preprocessing: ONE kernel replaces prep + hist + 3 scans +
// scatter + phase2.
//   phase 0: weight B-fragments -> wbuf, x -> bf16 (no sync needed)
//   phase 1: zero per-node degree counters (cur)
//   phase 2: histogram via global atomics
//   phase 3: two-level exclusive scan -> rowStart + cur
//   phase 4: direct atomic scatter -> csrSrc (order within node arbitrary;
//            fp32 sum reorder is << bf16 rounding noise)
// 256 blocks x 1024 threads: co-resident on 256 CUs, grid.sync() legal.
// ---------------------------------------------------------------------------
__global__ __launch_bounds__(COOP_THREADS) void preprocess_coop(
    const float* __restrict__ Wl0, const float* __restrict__ Wr0,
    const float* __restrict__ Wl1, const float* __restrict__ Wr1,
    const float* __restrict__ Wl2, const float* __restrict__ Wr2,
    ushort* __restrict__ wbuf,
    const float* __restrict__ x, ushort* __restrict__ xb,
    const int* __restrict__ src, const int* __restrict__ dst,
    int* __restrict__ rowStart, int* __restrict__ cur,
    int* __restrict__ blockSums, int* __restrict__ csrSrc,
    int E, int N, int NR) {
    cg::grid_group grid = cg::this_grid();
    __shared__ int sh[COOP_THREADS];

    const int t = threadIdx.x;
    const int b = blockIdx.x;
    const int gid = b * COOP_THREADS + t;
    const int GT = COOP_BLOCKS * COOP_THREADS;

    // ---- phase 0: weight fragments (first 3072 threads) ----
    if (gid < 3072) {
        int g = gid;                  // 3 sets * 16 frags * 64 lanes
        int set = g >> 10;
        int fl = g & 1023;
        int f = fl >> 6;              // frag id = s*4+ot
        int l = fl & 63;
        int s = f >> 2;
        int ot = f & 3;
        const float* Wl = (set == 0) ? Wl0 : (set == 1) ? Wl1 : Wl2;
        const float* Wr = (set == 0) ? Wr0 : (set == 1) ? Wr1 : Wr2;
        int o = ot * 16 + (l & 15);
        int k0 = s * 32 + (l >> 4) * 8;
        unsigned d[4];
#pragma unroll
        for (int p = 0; p < 4; ++p) {
            int ka = k0 + 2 * p, kb = k0 + 2 * p + 1;
            float va = (ka < 64) ? Wl[o * 64 + ka] : Wr[o * 64 + (ka - 64)];
            float vb = (kb < 64) ? Wl[o * 64 + kb] : Wr[o * 64 + (kb - 64)];
            d[p] = (unsigned)f2b(va) | ((unsigned)f2b(vb) << 16);
        }
        ((uint4*)wbuf)[g] = make_uint4(d[0], d[1], d[2], d[3]);
    }
    // ---- phase 0b: x -> bf16 (grid-stride float4) ----
    {
        int n4 = (N * F) >> 2;
        const float4* x4 = (const float4*)x;
        for (int i = gid; i < n4; i += GT) {
            float4 v = x4[i];
            uint2 o;
            o.x = (unsigned)f2b(v.x) | ((unsigned)f2b(v.y) << 16);
            o.y = (unsigned)f2b(v.z) | ((unsigned)f2b(v.w) << 16);
            ((uint2*)xb)[i] = o;
        }
    }
    // ---- phase 1: zero counters ----
    for (int i = gid; i < N; i += GT) cur[i] = 0;
    grid.sync();

    // ---- phase 2: histogram ----
    {
        const int4* d4 = (const int4*)dst;
        int n4 = E >> 2;
        for (int i = gid; i < n4; i += GT) {
            int4 v = d4[i];
            atomicAdd(&cur[v.x], 1);
            atomicAdd(&cur[v.y], 1);
            atomicAdd(&cur[v.z], 1);
            atomicAdd(&cur[v.w], 1);
        }
        for (int i = (E & ~3) + gid; i < E; i += GT) atomicAdd(&cur[dst[i]], 1);
    }
    grid.sync();

    // ---- phase 3a: per-block inclusive scan of 1024-chunk ----
    int i3 = b * COOP_THREADS + t;
    int v3 = (i3 < N) ? cur[i3] : 0;
    sh[t] = v3;
    __syncthreads();
    for (int off = 1; off < COOP_THREADS; off <<= 1) {
        int add = (t >= off) ? sh[t - off] : 0;
        __syncthreads();
        sh[t] += add;
        __syncthreads();
    }
    int incl = sh[t];
    if (t == COOP_THREADS - 1) blockSums[b] = incl;
    grid.sync();

    // ---- phase 3b: block 0 exclusive-scans the 256 block sums ----
    if (b == 0) {
        int bv = (t < COOP_BLOCKS) ? blockSums[t] : 0;
        sh[t] = bv;
        __syncthreads();
        for (int off = 1; off < COOP_BLOCKS; off <<= 1) {
            int add = (t >= off) ? sh[t - off] : 0;
            __syncthreads();
            sh[t] += add;
            __syncthreads();
        }
        if (t < COOP_BLOCKS) blockSums[t] = sh[t] - bv;
    }
    grid.sync();

    // ---- phase 3c: write exclusive offsets + padding ----
    {
        int off0 = blockSums[b];
        int excl = incl - v3 + off0;
        if (i3 < N) { rowStart[i3] = excl; cur[i3] = excl; }
        for (int j = gid; j <= NR; j += GT)
            if (j >= N) rowStart[j] = E;
    }
    grid.sync();

    // ---- phase 4: scatter ----
    {
        const int4* s4 = (const int4*)src;
        const int4* d4 = (const int4*)dst;
        int n4 = E >> 2;
        for (int i = gid; i < n4; i += GT) {
            int4 sv = s4[i];
            int4 dv = d4[i];
            csrSrc[atomicAdd(&cur[dv.x], 1)] = sv.x;
            csrSrc[atomicAdd(&cur[dv.y], 1)] = sv.y;
            csrSrc[atomicAdd(&cur[dv.z], 1)] = sv.z;
            csrSrc[atomicAdd(&cur[dv.w], 1)] = sv.w;
        }
        for (int i = (E & ~3) + gid; i < E; i += GT)
            csrSrc[atomicAdd(&cur[dst[i]], 1)] = src[i];
    }
}

// ---------------------------------------------------------------------------
// Fused layer: gather (register accumulate, 8 lanes/node, 4 nodes/thread)
//   -> LDS bf16 tile [128][72-stride] -> MFMA matvec -> transposed store.
// LDS buffer (18.4 KB) is reused for the output transpose (two 64-row halves)
// so 4 blocks/CU fit. flags: bit0 = tanh, bit1 = bf16 output.
// ---------------------------------------------------------------------------
__global__ __launch_bounds__(256, 4) void fused_layer(
    const ushort* __restrict__ hb, const int* __restrict__ rowStart,
    const int* __restrict__ csrSrc, const ushort* __restrict__ wbuf,
    const float* __restrict__ bl, void* __restrict__ out, int n, int flags) {
    // aggL: 128 rows x 72 ushorts (stride 144B: 16B-aligned b128, bank-spread)
    // reused after barrier as outT: 64 rows x 68 floats (17.4 KB <= 18.4 KB)
    __shared__ __align__(16) ushort smem[128 * 72];

    int t = threadIdx.x;
    int node0b = blockIdx.x * 128;
    const uint4* h16 = (const uint4*)hb;

    // ---- Phase A: gather into LDS ----
    {
        int c = t & 7;                 // 16B feature chunk
        int nlb = t >> 3;              // 0..31
#pragma unroll 1
        for (int r = 0; r < 4; ++r) {
            int nl = r * 32 + nlb;     // local node 0..127
            int node = node0b + nl;
            float a[8] = {0.f, 0.f, 0.f, 0.f, 0.f, 0.f, 0.f, 0.f};
            int e = rowStart[node];
            int end = rowStart[node + 1];
            for (; e + 3 < end; e += 4) {
                int s0 = csrSrc[e + 0];
                int s1 = csrSrc[e + 1];
                int s2 = csrSrc[e + 2];
                int s3 = csrSrc[e + 3];
                uint4 u0 = h16[(size_t)s0 * 8 + c];
                uint4 u1 = h16[(size_t)s1 * 8 + c];
                uint4 u2 = h16[(size_t)s2 * 8 + c];
                uint4 u3 = h16[(size_t)s3 * 8 + c];
                add8(a, u0); add8(a, u1); add8(a, u2); add8(a, u3);
            }
            for (; e < end; ++e) {
                uint4 u0 = h16[(size_t)csrSrc[e] * 8 + c];
                add8(a, u0);
            }
            unsigned d[4];
#pragma unroll
            for (int p = 0; p < 4; ++p)
                d[p] = (unsigned)f2b(a[2 * p]) | ((unsigned)f2b(a[2 * p + 1]) << 16);
            *(uint4*)(smem + nl * 72 + c * 8) = make_uint4(d[0], d[1], d[2], d[3]);
        }
    }
    __syncthreads();

    // ---- Phase B: MFMA matvec (A from LDS for agg, global for self) ----
    int w = t >> 6;
    int l = t & 63;
    int quad = l >> 4;
    int lo = l & 15;

    f32x4 acc[2][4];
#pragma unroll
    for (int ot = 0; ot < 4; ++ot) {
        float bv = bl[ot * 16 + lo];
        f32x4 bvv = {bv, bv, bv, bv};
        acc[0][ot] = bvv;
        acc[1][ot] = bvv;
    }

#pragma unroll
    for (int s = 0; s < 4; ++s) {
        bf16x8 A[2];
#pragma unroll
        for (int mt = 0; mt < 2; ++mt) {
            if (s < 2) {
                int nl = w * 32 + mt * 16 + lo;
                A[mt] = *(const bf16x8*)(smem + nl * 72 + s * 32 + quad * 8);
            } else {
                size_t node = (size_t)node0b + w * 32 + mt * 16 + lo;
                A[mt] = *(const bf16x8*)(hb + node * 64 + (s & 1) * 32 + quad * 8);
            }
        }
#pragma unroll
        for (int ot = 0; ot < 4; ++ot) {
            bf16x8 B = *(const bf16x8*)(wbuf + (((s * 4 + ot) * 64) + l) * 8);
#pragma unroll
            for (int mt = 0; mt < 2; ++mt)
                acc[mt][ot] = __builtin_amdgcn_mfma_f32_16x16x32_bf16(
                    A[mt], B, acc[mt][ot], 0, 0, 0);
        }
    }
    __syncthreads();               // all aggL reads done; smem becomes outT

    // ---- Epilogue: tanh + transpose via LDS, two 64-row halves ----
    float* outT = (float*)smem;
    int whalf = w >> 1;            // which half this wave's rows belong to
    int wrow = (w & 1) * 32;       // row base within the half

#pragma unroll
    for (int half = 0; half < 2; ++half) {
        if (whalf == half) {
#pragma unroll
            for (int mt = 0; mt < 2; ++mt) {
#pragma unroll
                for (int ot = 0; ot < 4; ++ot) {
                    f32x4 v = acc[mt][ot];
                    if (flags & 1) {
                        v[0] = tanhf(v[0]); v[1] = tanhf(v[1]);
                        v[2] = tanhf(v[2]); v[3] = tanhf(v[3]);
                    }
                    int row = wrow + mt * 16 + quad * 4;
                    int col = ot * 16 + lo;
#pragma unroll
                    for (int r = 0; r < 4; ++r)
                        outT[(row + r) * 68 + col] = v[r];
                }
            }
        }
        __syncthreads();
        // cooperative store of this half's 64 rows: 4 lanes/row x 16 cols
        int hr = t >> 2;
        int node = node0b + half * 64 + hr;
        if (node < n) {
            const float* srcp = &outT[hr * 68 + (t & 3) * 16];
            if (flags & 2) {
                uint4* o8 = (uint4*)out;     // bf16 row = 8 uint4
#pragma unroll
                for (int q = 0; q < 2; ++q) {
                    unsigned dd[4];
#pragma unroll
                    for (int p = 0; p < 4; ++p) {
                        float va = srcp[q * 8 + 2 * p];
                        float vb = srcp[q * 8 + 2 * p + 1];
                        dd[p] = (unsigned)f2b(va) | ((unsigned)f2b(vb) << 16);
                    }
                    o8[(size_t)node * 8 + (t & 3) * 2 + q] =
                        make_uint4(dd[0], dd[1], dd[2], dd[3]);
                }
            } else {
                float4* o16 = (float4*)out;  // fp32 row = 16 float4
#pragma unroll
                for (int q = 0; q < 4; ++q) {
                    float4 v = *(const float4*)(srcp + q * 4);
                    o16[(size_t)node * 16 + (t & 3) * 4 + q] = v;
                }
            }
        }
        if (half == 0) __syncthreads();      // protect outT before half-1 writes
    }
}

// ---------------------------------------------------------------------------
// Launch
// ---------------------------------------------------------------------------
extern "C" void kernel_launch(void* const* d_in, const int* in_sizes, int n_in,
                              void* d_out, int out_size, void* d_ws, size_t ws_size,
                              hipStream_t stream) {
    const float* x      = (const float*)d_in[0];
    const int*   edges  = (const int*)d_in[1];
    const float* Wl_in  = (const float*)d_in[2];
    const float* bl_in  = (const float*)d_in[3];
    const float* Wr_in  = (const float*)d_in[4];
    const float* Wl_med = (const float*)d_in[5];
    const float* bl_med = (const float*)d_in[6];
    const float* Wr_med = (const float*)d_in[7];
    const float* Wl_out = (const float*)d_in[8];
    const float* bl_out = (const float*)d_in[9];
    const float* Wr_out = (const float*)d_in[10];

    const int N = in_sizes[0] / F;
    const int E = in_sizes[1] / 2;
    const int* srcp = edges;
    const int* dstp = edges + E;

    const int nf = (N + 127) >> 7;               // 128-node tiles (782)
    const int NR = nf * 128;                     // padded node count

    // Workspace layout (16B-aligned chunks)
    ushort*  wbuf      = (ushort*)d_ws;                        // 3*8192 bf16
    ushort*  xb        = wbuf + 3 * 8192;                      // NR*F bf16
    ushort*  hAb       = xb + (size_t)NR * F;                  // NR*F bf16
    ushort*  hBb       = hAb + (size_t)NR * F;                 // NR*F bf16
    int*     rowStart  = (int*)(hBb + (size_t)NR * F);         // NR+16
    int*     cur       = rowStart + NR + 16;                   // NR
    int*     blockSums = cur + NR;                             // 1024 pad
    int*     csrSrc    = blockSums + 1024;                     // E

    int Ei = E, Ni = N, NRi = NR;
    void* args[] = {
        (void*)&Wl_in, (void*)&Wr_in, (void*)&Wl_med, (void*)&Wr_med,
        (void*)&Wl_out, (void*)&Wr_out, (void*)&wbuf,
        (void*)&x, (void*)&xb,
        (void*)&srcp, (void*)&dstp,
        (void*)&rowStart, (void*)&cur, (void*)&blockSums, (void*)&csrSrc,
        (void*)&Ei, (void*)&Ni, (void*)&NRi,
    };
    hipLaunchCooperativeKernel(preprocess_coop, dim3(COOP_BLOCKS),
                               dim3(COOP_THREADS), args, 0u, stream);

    // Fused layers: gather + MFMA matvec in one kernel per layer
    fused_layer<<<nf, 256, 0, stream>>>(xb,  rowStart, csrSrc, wbuf,         bl_in,  hAb,   N, 3);
    fused_layer<<<nf, 256, 0, stream>>>(hAb, rowStart, csrSrc, wbuf + 8192,  bl_med, hBb,   N, 3);
    fused_layer<<<nf, 256, 0, stream>>>(hBb, rowStart, csrSrc, wbuf + 8192,  bl_med, hAb,   N, 3);
    fused_layer<<<nf, 256, 0, stream>>>(hAb, rowStart, csrSrc, wbuf + 16384, bl_out, d_out, N, 0);
}

// Round 3
// 269.709 us; speedup vs baseline: 2.0734x; 2.0734x over previous
//
#include <hip/hip_runtime.h>
#include <cstdint>

#define F 64
#define TILE1 8192     // edges per bucketing tile
#define MAXFB 1024     // max fine buckets (supports N <= 131072)
#define SCAN_BLK 1024

typedef short bf16x8 __attribute__((ext_vector_type(8)));
typedef float f32x4  __attribute__((ext_vector_type(4)));

// ---------------------------------------------------------------------------
// bf16 helpers
// ---------------------------------------------------------------------------
__device__ __forceinline__ unsigned short f2b(float f) {     // RNE round
    unsigned u = __float_as_uint(f);
    unsigned r = u + 0x7fffu + ((u >> 16) & 1u);
    return (unsigned short)(r >> 16);
}
__device__ __forceinline__ void add8(float* a, uint4 u) {
    const unsigned* p = (const unsigned*)&u;
#pragma unroll
    for (int i = 0; i < 4; ++i) {
        a[2 * i + 0] += __uint_as_float(p[i] << 16);
        a[2 * i + 1] += __uint_as_float(p[i] & 0xffff0000u);
    }
}

// ---------------------------------------------------------------------------
// Merged prep + hist:
//   blocks [0,12)           : weight B-fragments -> wbuf
//   blocks [12, 12+NB1)     : per-tile histogram by fine bucket (LDS atomics)
//   blocks [12+NB1, ...)    : x -> bf16
// ---------------------------------------------------------------------------
__global__ __launch_bounds__(256) void prep_hist_kernel(
    const float* __restrict__ Wl0, const float* __restrict__ Wr0,
    const float* __restrict__ Wl1, const float* __restrict__ Wr1,
    const float* __restrict__ Wl2, const float* __restrict__ Wr2,
    ushort* __restrict__ wbuf,
    const float* __restrict__ x, ushort* __restrict__ xb, int nElem,
    const int* __restrict__ dst, int* __restrict__ binMat,
    int E, int NB1, int nf) {
    __shared__ int h[MAXFB];
    int b = blockIdx.x;
    int t = threadIdx.x;
    if (b < 12) {
        int g = b * 256 + t;          // g < 3072 = 3 sets * 16 frags * 64 lanes
        int set = g >> 10;
        int fl = g & 1023;
        int f = fl >> 6;              // frag id = s*4+ot
        int l = fl & 63;
        int s = f >> 2;
        int ot = f & 3;
        const float* Wl = (set == 0) ? Wl0 : (set == 1) ? Wl1 : Wl2;
        const float* Wr = (set == 0) ? Wr0 : (set == 1) ? Wr1 : Wr2;
        int o = ot * 16 + (l & 15);
        int k0 = s * 32 + (l >> 4) * 8;
        unsigned d[4];
#pragma unroll
        for (int p = 0; p < 4; ++p) {
            int ka = k0 + 2 * p, kb = k0 + 2 * p + 1;
            float va = (ka < 64) ? Wl[o * 64 + ka] : Wr[o * 64 + (ka - 64)];
            float vb = (kb < 64) ? Wl[o * 64 + kb] : Wr[o * 64 + (kb - 64)];
            d[p] = (unsigned)f2b(va) | ((unsigned)f2b(vb) << 16);
        }
        ((uint4*)wbuf)[g] = make_uint4(d[0], d[1], d[2], d[3]);
    } else if (b < 12 + NB1) {
        int tb = b - 12;              // tile index
        for (int i = t; i < nf; i += 256) h[i] = 0;
        __syncthreads();
        int base = tb * TILE1;
        int end = min(base + TILE1, E);
        const int4* d4 = (const int4*)dst;
        int n4 = (end - base) >> 2;
        int b4 = base >> 2;
        for (int k = t; k < n4; k += 256) {
            int4 v = d4[b4 + k];
            atomicAdd(&h[v.x >> 7], 1);
            atomicAdd(&h[v.y >> 7], 1);
            atomicAdd(&h[v.z >> 7], 1);
            atomicAdd(&h[v.w >> 7], 1);
        }
        __syncthreads();
        for (int i = t; i < nf; i += 256) binMat[i * NB1 + tb] = h[i];
    } else {
        int i = (b - 12 - NB1) * 256 + t;   // float4 index
        int n4 = nElem >> 2;
        if (i < n4) {
            float4 v = ((const float4*)x)[i];
            uint2 o;
            o.x = (unsigned)f2b(v.x) | ((unsigned)f2b(v.y) << 16);
            o.y = (unsigned)f2b(v.z) | ((unsigned)f2b(v.w) << 16);
            ((uint2*)xb)[i] = o;
        }
    }
}

// ---------------------------------------------------------------------------
// Scan level 1: per-1024-chunk exclusive scan (in-place) + chunk sums.
// The chunk-sum correction is applied LAZILY by consumers:
//   full_excl[j] = binMat[j] + blockSums[j >> 10]
// ---------------------------------------------------------------------------
__global__ __launch_bounds__(SCAN_BLK) void scan_blocks_kernel(
    int* __restrict__ a, int* __restrict__ blockSums, int len) {
    __shared__ int sh[SCAN_BLK];
    int t = threadIdx.x;
    int i = blockIdx.x * SCAN_BLK + t;
    int v = (i < len) ? a[i] : 0;
    sh[t] = v;
    __syncthreads();
    for (int off = 1; off < SCAN_BLK; off <<= 1) {
        int add = (t >= off) ? sh[t - off] : 0;
        __syncthreads();
        sh[t] += add;
        __syncthreads();
    }
    int incl = sh[t];
    if (i < len) a[i] = incl - v;
    if (t == SCAN_BLK - 1) blockSums[blockIdx.x] = incl;
}

__global__ __launch_bounds__(SCAN_BLK) void scan_sums_kernel(
    int* __restrict__ blockSums, int nb) {
    __shared__ int sh[SCAN_BLK];
    int t = threadIdx.x;
    int v = (t < nb) ? blockSums[t] : 0;
    sh[t] = v;
    __syncthreads();
    for (int off = 1; off < SCAN_BLK; off <<= 1) {
        int add = (t >= off) ? sh[t - off] : 0;
        __syncthreads();
        sh[t] += add;
        __syncthreads();
    }
    if (t < nb) blockSums[t] = sh[t] - v;
}

// ---------------------------------------------------------------------------
// Scatter: deterministic placement into fine-bucket-sorted stage2.
// Packed word: (dst & 127) << 17 | src   (needs N <= 131072)
// ---------------------------------------------------------------------------
__global__ __launch_bounds__(256) void scatter_kernel(
    const int* __restrict__ src, const int* __restrict__ dst,
    const int* __restrict__ binMat, const int* __restrict__ blockSums,
    unsigned* __restrict__ stage2, int E, int NB1, int nf) {
    __shared__ int cur[MAXFB];
    int t = threadIdx.x;
    for (int i = t; i < nf; i += 256) {
        int j = i * NB1 + blockIdx.x;
        cur[i] = binMat[j] + blockSums[j >> 10];
    }
    __syncthreads();
    int base = blockIdx.x * TILE1;
    int end = min(base + TILE1, E);
    const int4* s4 = (const int4*)src;
    const int4* d4 = (const int4*)dst;
    int n4 = (end - base) >> 2;
    int b4 = base >> 2;
    for (int k = t; k < n4; k += 256) {
        int4 s = s4[b4 + k];
        int4 d = d4[b4 + k];
        int p0 = atomicAdd(&cur[d.x >> 7], 1);
        int p1 = atomicAdd(&cur[d.y >> 7], 1);
        int p2 = atomicAdd(&cur[d.z >> 7], 1);
        int p3 = atomicAdd(&cur[d.w >> 7], 1);
        stage2[p0] = ((unsigned)(d.x & 127) << 17) | (unsigned)s.x;
        stage2[p1] = ((unsigned)(d.y & 127) << 17) | (unsigned)s.y;
        stage2[p2] = ((unsigned)(d.z & 127) << 17) | (unsigned)s.z;
        stage2[p3] = ((unsigned)(d.w & 127) << 17) | (unsigned)s.w;
    }
}

// ---------------------------------------------------------------------------
// Phase 2: one block per fine bucket (128 nodes) -> csrSrc + rowStart.
// ---------------------------------------------------------------------------
__global__ __launch_bounds__(256) void phase2_kernel(
    const unsigned* __restrict__ stage2, const int* __restrict__ binMat,
    const int* __restrict__ blockSums,
    int* __restrict__ csrSrc, int* __restrict__ rowStart,
    int E, int NB1, int nf) {
    __shared__ int cnt[128];
    __shared__ int pre[129];
    __shared__ int cur[128];
    int b = blockIdx.x;
    int t = threadIdx.x;
    int j0 = b * NB1;
    int s = binMat[j0] + blockSums[j0 >> 10];
    int e2 = E;
    if (b + 1 < nf) {
        int j1 = (b + 1) * NB1;
        e2 = binMat[j1] + blockSums[j1 >> 10];
    }
    if (t < 128) cnt[t] = 0;
    __syncthreads();
    for (int i = s + t; i < e2; i += 256)
        atomicAdd(&cnt[(stage2[i] >> 17) & 127], 1);
    __syncthreads();
    if (t < 128) pre[t + 1] = cnt[t];
    if (t == 0) pre[0] = 0;
    __syncthreads();
    for (int off = 1; off < 128; off <<= 1) {
        int v = 0;
        if (t < 128 && (t + 1) > off) v = pre[t + 1 - off];
        __syncthreads();
        if (t < 128 && (t + 1) > off) pre[t + 1] += v;
        __syncthreads();
    }
    if (t < 128) cur[t] = pre[t];
    if (t < 129) rowStart[b * 128 + t] = s + pre[t];
    __syncthreads();
    for (int i = s + t; i < e2; i += 256) {
        unsigned w = stage2[i];
        int pos = atomicAdd(&cur[(w >> 17) & 127], 1);
        csrSrc[s + pos] = (int)(w & 0x1FFFFu);
    }
}

// ---------------------------------------------------------------------------
// Fused layer (512 threads = 8 waves per 128-node tile):
//   Phase A: gather, 8 lanes/node, 2 nodes/thread -> LDS bf16 [128][72]
//   Phase B: MFMA matvec, each wave owns one 16-node m-tile
//   Epilogue: tanh + transpose via reused LDS, two 64-row halves.
// 8 waves/block doubles gather-phase occupancy vs the 4-wave version
// (grid is fixed at nf blocks; gather is latency-bound).
// flags: bit0 = tanh, bit1 = bf16 output.
// ---------------------------------------------------------------------------
__global__ __launch_bounds__(512, 4) void fused_layer(
    const ushort* __restrict__ hb, const int* __restrict__ rowStart,
    const int* __restrict__ csrSrc, const ushort* __restrict__ wbuf,
    const float* __restrict__ bl, void* __restrict__ out, int n, int flags) {
    // aggL: 128 rows x 72 ushorts (stride 144B: 16B-aligned b128, bank-spread)
    // reused after barrier as outT: 64 rows x 68 floats (17.4 KB <= 18.4 KB)
    __shared__ __align__(16) ushort smem[128 * 72];

    int t = threadIdx.x;
    int node0b = blockIdx.x * 128;
    const uint4* h16 = (const uint4*)hb;

    // ---- Phase A: gather into LDS ----
    {
        int c = t & 7;                 // 16B feature chunk
        int nlb = t >> 3;              // 0..63
#pragma unroll 1
        for (int r = 0; r < 2; ++r) {
            int nl = r * 64 + nlb;     // local node 0..127
            int node = node0b + nl;
            float a[8] = {0.f, 0.f, 0.f, 0.f, 0.f, 0.f, 0.f, 0.f};
            int e = rowStart[node];
            int end = rowStart[node + 1];
            for (; e + 3 < end; e += 4) {
                int s0 = csrSrc[e + 0];
                int s1 = csrSrc[e + 1];
                int s2 = csrSrc[e + 2];
                int s3 = csrSrc[e + 3];
                uint4 u0 = h16[(size_t)s0 * 8 + c];
                uint4 u1 = h16[(size_t)s1 * 8 + c];
                uint4 u2 = h16[(size_t)s2 * 8 + c];
                uint4 u3 = h16[(size_t)s3 * 8 + c];
                add8(a, u0); add8(a, u1); add8(a, u2); add8(a, u3);
            }
            for (; e < end; ++e) {
                uint4 u0 = h16[(size_t)csrSrc[e] * 8 + c];
                add8(a, u0);
            }
            unsigned d[4];
#pragma unroll
            for (int p = 0; p < 4; ++p)
                d[p] = (unsigned)f2b(a[2 * p]) | ((unsigned)f2b(a[2 * p + 1]) << 16);
            *(uint4*)(smem + nl * 72 + c * 8) = make_uint4(d[0], d[1], d[2], d[3]);
        }
    }
    __syncthreads();

    // ---- Phase B: MFMA matvec (A from LDS for agg, global for self) ----
    int w = t >> 6;                    // wave 0..7 -> 16-node m-tile
    int l = t & 63;
    int quad = l >> 4;
    int lo = l & 15;

    f32x4 acc[4];
#pragma unroll
    for (int ot = 0; ot < 4; ++ot) {
        float bv = bl[ot * 16 + lo];
        f32x4 bvv = {bv, bv, bv, bv};
        acc[ot] = bvv;
    }

#pragma unroll
    for (int s = 0; s < 4; ++s) {
        bf16x8 A;
        if (s < 2) {
            int nl = w * 16 + lo;
            A = *(const bf16x8*)(smem + nl * 72 + s * 32 + quad * 8);
        } else {
            size_t node = (size_t)node0b + w * 16 + lo;
            A = *(const bf16x8*)(hb + node * 64 + (s & 1) * 32 + quad * 8);
        }
#pragma unroll
        for (int ot = 0; ot < 4; ++ot) {
            bf16x8 B = *(const bf16x8*)(wbuf + (((s * 4 + ot) * 64) + l) * 8);
            acc[ot] = __builtin_amdgcn_mfma_f32_16x16x32_bf16(A, B, acc[ot], 0, 0, 0);
        }
    }
    __syncthreads();               // all aggL reads done; smem becomes outT

    // ---- Epilogue: tanh + transpose via LDS, two 64-row halves ----
    float* outT = (float*)smem;
    int whalf = w >> 2;            // which half this wave's rows belong to
    int wrow = (w & 3) * 16;       // row base within the half

#pragma unroll
    for (int half = 0; half < 2; ++half) {
        if (whalf == half) {
#pragma unroll
            for (int ot = 0; ot < 4; ++ot) {
                f32x4 v = acc[ot];
                if (flags & 1) {
                    v[0] = tanhf(v[0]); v[1] = tanhf(v[1]);
                    v[2] = tanhf(v[2]); v[3] = tanhf(v[3]);
                }
                int row = wrow + quad * 4;
                int col = ot * 16 + lo;
#pragma unroll
                for (int r = 0; r < 4; ++r)
                    outT[(row + r) * 68 + col] = v[r];
            }
        }
        __syncthreads();
        // cooperative store of this half's 64 rows: 8 lanes/row x 8 cols
        int hr = t >> 3;
        int node = node0b + half * 64 + hr;
        if (node < n) {
            const float* srcp = &outT[hr * 68 + (t & 7) * 8];
            if (flags & 2) {
                uint4* o8 = (uint4*)out;     // bf16 row = 8 uint4
                unsigned dd[4];
#pragma unroll
                for (int p = 0; p < 4; ++p) {
                    float va = srcp[2 * p];
                    float vb = srcp[2 * p + 1];
                    dd[p] = (unsigned)f2b(va) | ((unsigned)f2b(vb) << 16);
                }
                o8[(size_t)node * 8 + (t & 7)] = make_uint4(dd[0], dd[1], dd[2], dd[3]);
            } else {
                float4* o16 = (float4*)out;  // fp32 row = 16 float4
#pragma unroll
                for (int q = 0; q < 2; ++q) {
                    float4 v = *(const float4*)(srcp + q * 4);
                    o16[(size_t)node * 16 + (t & 7) * 2 + q] = v;
                }
            }
        }
        if (half == 0) __syncthreads();      // protect outT before half-1 writes
    }
}

// ---------------------------------------------------------------------------
// Launch
// ---------------------------------------------------------------------------
extern "C" void kernel_launch(void* const* d_in, const int* in_sizes, int n_in,
                              void* d_out, int out_size, void* d_ws, size_t ws_size,
                              hipStream_t stream) {
    const float* x      = (const float*)d_in[0];
    const int*   edges  = (const int*)d_in[1];
    const float* Wl_in  = (const float*)d_in[2];
    const float* bl_in  = (const float*)d_in[3];
    const float* Wr_in  = (const float*)d_in[4];
    const float* Wl_med = (const float*)d_in[5];
    const float* bl_med = (const float*)d_in[6];
    const float* Wr_med = (const float*)d_in[7];
    const float* Wl_out = (const float*)d_in[8];
    const float* bl_out = (const float*)d_in[9];
    const float* Wr_out = (const float*)d_in[10];

    const int N = in_sizes[0] / F;
    const int E = in_sizes[1] / 2;
    const int* src = edges;
    const int* dst = edges + E;

    const int nf  = (N + 127) >> 7;              // fine buckets (782)
    const int NB1 = (E + TILE1 - 1) / TILE1;     // bucketing tiles (147)
    const int NR  = nf * 128;                    // padded node count
    const int scanLen = nf * NB1;
    const int nbScan = (scanLen + SCAN_BLK - 1) / SCAN_BLK;

    // Workspace layout (16B-aligned chunks)
    ushort*  wbuf      = (ushort*)d_ws;                        // 3*8192 bf16
    ushort*  xb        = wbuf + 3 * 8192;                      // NR*F bf16
    ushort*  hAb       = xb + (size_t)NR * F;                  // NR*F bf16
    ushort*  hBb       = hAb + (size_t)NR * F;                 // NR*F bf16
    int*     rowStart  = (int*)(hBb + (size_t)NR * F);         // NR+2
    int*     blockSums = rowStart + NR + 2;                    // nbScan (<=1024)
    int*     binMat    = blockSums + SCAN_BLK;                 // nf*NB1
    unsigned* stage2   = (unsigned*)(binMat + scanLen);        // E
    int*     csrSrc    = (int*)(stage2 + E);                   // E

    const int prep_blocks = 12 + NB1 + (N * F / 4 + 255) / 256;

    // Preprocessing: prep+hist merged, 2-level scan (lazy add), scatter, phase2
    prep_hist_kernel<<<prep_blocks, 256, 0, stream>>>(
        Wl_in, Wr_in, Wl_med, Wr_med, Wl_out, Wr_out, wbuf, x, xb, N * F,
        dst, binMat, E, NB1, nf);
    scan_blocks_kernel<<<nbScan, SCAN_BLK, 0, stream>>>(binMat, blockSums, scanLen);
    scan_sums_kernel<<<1, SCAN_BLK, 0, stream>>>(blockSums, nbScan);
    scatter_kernel<<<NB1, 256, 0, stream>>>(src, dst, binMat, blockSums, stage2, E, NB1, nf);
    phase2_kernel<<<nf, 256, 0, stream>>>(stage2, binMat, blockSums, csrSrc, rowStart, E, NB1, nf);

    // Fused layers: gather + MFMA matvec in one kernel per layer
    fused_layer<<<nf, 512, 0, stream>>>(xb,  rowStart, csrSrc, wbuf,         bl_in,  hAb,   N, 3);
    fused_layer<<<nf, 512, 0, stream>>>(hAb, rowStart, csrSrc, wbuf + 8192,  bl_med, hBb,   N, 3);
    fused_layer<<<nf, 512, 0, stream>>>(hBb, rowStart, csrSrc, wbuf + 8192,  bl_med, hAb,   N, 3);
    fused_layer<<<nf, 512, 0, stream>>>(hAb, rowStart, csrSrc, wbuf + 16384, bl_out, d_out, N, 0);
}